// Round 5
// baseline (112.892 us; speedup 1.0000x reference)
//
#include <hip/hip_runtime.h>

// Valid 3x3 cross-correlation + scalar bias.
// x: [8192][8192] f32 -> out: [8190][8190] f32.
// Memory-bound. Steady-state traffic ~430 MB -> ~68 us @ 6.3 TB/s.
//
// History:
//  R1: 212 us — latency-bound (VGPR=16, 1.9 TB/s).
//  R2: 93 us — 4x8 per-thread tile, NT stores.
//  R3: 120 us — dropped NT: REGRESSION (output write-allocate evicted input L3).
//  R4: 93 us — NT + parity-aligned store widths: neutral (WRITE 292 MB is
//      row-boundary partial lines, a ~5% structural tax).
//  R5 (this): software-pipelined vertical strip. Each thread owns an 8-col
//      group and walks 8 consecutive 4-row tiles (32 rows): next tile's rows
//      load during current tile's ~576-cycle FMA phase (sustained MLP), and
//      the 2-row halo is register-reused (per-thread reads 1.5x -> 1.06x).
//      Fully unrolled so rotation is register renaming.

static constexpr int H  = 8192;
static constexpr int W  = 8192;
static constexpr int OH = H - 2;   // 8190
static constexpr int OW = W - 2;   // 8190
static constexpr int TILES = 8;    // 4-row tiles per thread -> 32 rows/thread

typedef float f32x4 __attribute__((ext_vector_type(4)));
typedef float f32x2 __attribute__((ext_vector_type(2)));

__device__ __forceinline__ void loadRow(float (&dst)[10],
                                        const float* __restrict__ x,
                                        int rr, int c, bool colFast)
{
    rr = (rr < H) ? rr : (H - 1);           // clamped rows feed only OOB outputs
    const float* row = x + (size_t)rr * W + c;
    const f32x4 va = *reinterpret_cast<const f32x4*>(row);
    const f32x4 vb = *reinterpret_cast<const f32x4*>(row + 4);
    dst[0] = va.x; dst[1] = va.y; dst[2] = va.z; dst[3] = va.w;
    dst[4] = vb.x; dst[5] = vb.y; dst[6] = vb.z; dst[7] = vb.w;
    if (colFast) {
        const f32x2 vc = *reinterpret_cast<const f32x2*>(row + 8);
        dst[8] = vc.x; dst[9] = vc.y;
    } else {
        dst[8] = 0.0f; dst[9] = 0.0f;
    }
}

// blockDim = (64, 4): block covers 512 cols x 128 rows.
// gridDim  = (16, 64).
__global__ __launch_bounds__(256) void conv3x3_kernel(
    const float* __restrict__ x,
    const float* __restrict__ w,
    const float* __restrict__ bias,
    float* __restrict__ out)
{
    const int c  = (blockIdx.x * 64 + (int)threadIdx.x) * 8;   // col group base
    const int r0 = (blockIdx.y * 4 + (int)threadIdx.y) * (4 * TILES); // row strip base (mult of 32)
    if (c >= OW || r0 >= OH) return;

    float wk[3][3];
    #pragma unroll
    for (int i = 0; i < 3; ++i)
        #pragma unroll
        for (int j = 0; j < 3; ++j)
            wk[i][j] = w[i * 3 + j];
    const float b = bias[0];

    // Last col-group (c == 8184) lacks cols c+8..9; they only feed OOB outputs.
    const bool colFast = (c + 10 <= W);

    // Prologue: rows r0..r0+5.
    float cur[6][10];
    #pragma unroll
    for (int t = 0; t < 6; ++t)
        loadRow(cur[t], x, r0 + t, c, colFast);

    #pragma unroll
    for (int it = 0; it < TILES; ++it) {
        const int r = r0 + it * 4;

        // Prefetch next tile's 4 rows (r+6..r+9) — in flight during compute.
        float nxt[4][10];
        if (it + 1 < TILES) {
            #pragma unroll
            for (int t = 0; t < 4; ++t)
                loadRow(nxt[t], x, r + 6 + t, c, colFast);
        }

        float acc[4][8];
        #pragma unroll
        for (int i = 0; i < 4; ++i)
            #pragma unroll
            for (int j = 0; j < 8; ++j)
                acc[i][j] = b;

        #pragma unroll
        for (int i = 0; i < 4; ++i) {
            #pragma unroll
            for (int kr = 0; kr < 3; ++kr) {
                const int t = i + kr;
                const float k0 = wk[kr][0], k1 = wk[kr][1], k2 = wk[kr][2];
                #pragma unroll
                for (int j = 0; j < 8; ++j)
                    acc[i][j] = fmaf(k0, cur[t][j],
                                fmaf(k1, cur[t][j + 1],
                                fmaf(k2, cur[t][j + 2], acc[i][j])));
            }
        }

        // Stores: out row parity == i parity (r multiple of 4).
        #pragma unroll
        for (int i = 0; i < 4; ++i) {
            if (r + i < OH) {
                float* orow = out + (size_t)(r + i) * OW + c;
                if (c + 8 <= OW) {
                    if ((i & 1) == 0) {
                        f32x4 o0 = { acc[i][0], acc[i][1], acc[i][2], acc[i][3] };
                        f32x4 o1 = { acc[i][4], acc[i][5], acc[i][6], acc[i][7] };
                        __builtin_nontemporal_store(o0, reinterpret_cast<f32x4*>(orow));
                        __builtin_nontemporal_store(o1, reinterpret_cast<f32x4*>(orow + 4));
                    } else {
                        f32x2 o0 = { acc[i][0], acc[i][1] };
                        f32x2 o1 = { acc[i][2], acc[i][3] };
                        f32x2 o2 = { acc[i][4], acc[i][5] };
                        f32x2 o3 = { acc[i][6], acc[i][7] };
                        __builtin_nontemporal_store(o0, reinterpret_cast<f32x2*>(orow));
                        __builtin_nontemporal_store(o1, reinterpret_cast<f32x2*>(orow + 2));
                        __builtin_nontemporal_store(o2, reinterpret_cast<f32x2*>(orow + 4));
                        __builtin_nontemporal_store(o3, reinterpret_cast<f32x2*>(orow + 6));
                    }
                } else {
                    // c == 8184: outputs j=0..5 valid.
                    #pragma unroll
                    for (int j = 0; j < 6; ++j)
                        __builtin_nontemporal_store(acc[i][j], orow + j);
                }
            }
        }

        // Rotate rows: halo reuse. Full unroll -> pure register renaming.
        if (it + 1 < TILES) {
            #pragma unroll
            for (int q = 0; q < 10; ++q) {
                cur[0][q] = cur[4][q];
                cur[1][q] = cur[5][q];
            }
            #pragma unroll
            for (int t = 0; t < 4; ++t)
                #pragma unroll
                for (int q = 0; q < 10; ++q)
                    cur[2 + t][q] = nxt[t][q];
        }
    }
}

extern "C" void kernel_launch(void* const* d_in, const int* in_sizes, int n_in,
                              void* d_out, int out_size, void* d_ws, size_t ws_size,
                              hipStream_t stream) {
    const float* x    = (const float*)d_in[0];
    const float* w    = (const float*)d_in[1];
    const float* bias = (const float*)d_in[2];
    float* out        = (float*)d_out;

    dim3 block(64, 4, 1);
    dim3 grid((OW + 512 - 1) / 512,            // 16
              (OH + 128 - 1) / 128,            // 64
              1);
    conv3x3_kernel<<<grid, block, 0, stream>>>(x, w, bias, out);
}

// Round 6
// 99.473 us; speedup vs baseline: 1.1349x; 1.1349x over previous
//
#include <hip/hip_runtime.h>

// Valid 3x3 cross-correlation + scalar bias.
// x: [8192][8192] f32 -> out: [8190][8190] f32.
// Memory-bound. Steady-state traffic ~430 MB -> ~68 us @ 6.3 TB/s.
//
// History:
//  R1: 212 us — latency-bound (VGPR=16, 1.9 TB/s).
//  R2: 93 us — 4x8 per-thread tile, NT stores.
//  R3: 120 us — dropped NT: REGRESSION (output write-allocate evicted input L3).
//  R4: 93 us — NT + parity-aligned store widths (WRITE 292 MB = floor + ~9%
//      partial-line tax). 51% occupancy, 4.65 TB/s: load-drain/compute phase
//      sync caps BW duty at ~60%.
//  R5: 113 us — TILES=8 pipeline: CONFOUNDED regression. 32 rows/thread ->
//      only 1024 blocks = 16 waves/CU grid-limited (occ 25%). Pipeline thesis
//      untested.
//  R6 (this): TILES=2 pipeline. 8 rows/thread, grid 16x256=4096 blocks (no
//      grid starvation), prefetch next 4 rows during current tile's FMA phase,
//      2-row halo register-reused. Single variable vs R4.

static constexpr int H  = 8192;
static constexpr int W  = 8192;
static constexpr int OH = H - 2;   // 8190
static constexpr int OW = W - 2;   // 8190
static constexpr int TILES = 2;    // 4-row tiles per thread -> 8 rows/thread

typedef float f32x4 __attribute__((ext_vector_type(4)));
typedef float f32x2 __attribute__((ext_vector_type(2)));

__device__ __forceinline__ void loadRow(float (&dst)[10],
                                        const float* __restrict__ x,
                                        int rr, int c, bool colFast)
{
    rr = (rr < H) ? rr : (H - 1);           // clamped rows feed only OOB outputs
    const float* row = x + (size_t)rr * W + c;
    const f32x4 va = *reinterpret_cast<const f32x4*>(row);
    const f32x4 vb = *reinterpret_cast<const f32x4*>(row + 4);
    dst[0] = va.x; dst[1] = va.y; dst[2] = va.z; dst[3] = va.w;
    dst[4] = vb.x; dst[5] = vb.y; dst[6] = vb.z; dst[7] = vb.w;
    if (colFast) {
        const f32x2 vc = *reinterpret_cast<const f32x2*>(row + 8);
        dst[8] = vc.x; dst[9] = vc.y;
    } else {
        dst[8] = 0.0f; dst[9] = 0.0f;
    }
}

// blockDim = (64, 4): block covers 512 cols x 32 rows.
// gridDim  = (16, 256).
__global__ __launch_bounds__(256) void conv3x3_kernel(
    const float* __restrict__ x,
    const float* __restrict__ w,
    const float* __restrict__ bias,
    float* __restrict__ out)
{
    const int c  = (blockIdx.x * 64 + (int)threadIdx.x) * 8;          // col group base
    const int r0 = (blockIdx.y * 4 + (int)threadIdx.y) * (4 * TILES); // row strip base (mult of 8)
    if (c >= OW || r0 >= OH) return;

    float wk[3][3];
    #pragma unroll
    for (int i = 0; i < 3; ++i)
        #pragma unroll
        for (int j = 0; j < 3; ++j)
            wk[i][j] = w[i * 3 + j];
    const float b = bias[0];

    // Last col-group (c == 8184) lacks cols c+8..9; they only feed OOB outputs.
    const bool colFast = (c + 10 <= W);

    // Prologue: rows r0..r0+5.
    float cur[6][10];
    #pragma unroll
    for (int t = 0; t < 6; ++t)
        loadRow(cur[t], x, r0 + t, c, colFast);

    #pragma unroll
    for (int it = 0; it < TILES; ++it) {
        const int r = r0 + it * 4;

        // Prefetch next tile's 4 rows (r+6..r+9) — in flight during compute.
        float nxt[4][10];
        if (it + 1 < TILES) {
            #pragma unroll
            for (int t = 0; t < 4; ++t)
                loadRow(nxt[t], x, r + 6 + t, c, colFast);
        }

        float acc[4][8];
        #pragma unroll
        for (int i = 0; i < 4; ++i)
            #pragma unroll
            for (int j = 0; j < 8; ++j)
                acc[i][j] = b;

        #pragma unroll
        for (int i = 0; i < 4; ++i) {
            #pragma unroll
            for (int kr = 0; kr < 3; ++kr) {
                const int t = i + kr;
                const float k0 = wk[kr][0], k1 = wk[kr][1], k2 = wk[kr][2];
                #pragma unroll
                for (int j = 0; j < 8; ++j)
                    acc[i][j] = fmaf(k0, cur[t][j],
                                fmaf(k1, cur[t][j + 1],
                                fmaf(k2, cur[t][j + 2], acc[i][j])));
            }
        }

        // Stores: out row parity == i parity (r multiple of 4).
        #pragma unroll
        for (int i = 0; i < 4; ++i) {
            if (r + i < OH) {
                float* orow = out + (size_t)(r + i) * OW + c;
                if (c + 8 <= OW) {
                    if ((i & 1) == 0) {
                        // even output row: 16B-aligned -> NT dwordx4
                        f32x4 o0 = { acc[i][0], acc[i][1], acc[i][2], acc[i][3] };
                        f32x4 o1 = { acc[i][4], acc[i][5], acc[i][6], acc[i][7] };
                        __builtin_nontemporal_store(o0, reinterpret_cast<f32x4*>(orow));
                        __builtin_nontemporal_store(o1, reinterpret_cast<f32x4*>(orow + 4));
                    } else {
                        // odd output row: 8B-aligned -> NT dwordx2
                        f32x2 o0 = { acc[i][0], acc[i][1] };
                        f32x2 o1 = { acc[i][2], acc[i][3] };
                        f32x2 o2 = { acc[i][4], acc[i][5] };
                        f32x2 o3 = { acc[i][6], acc[i][7] };
                        __builtin_nontemporal_store(o0, reinterpret_cast<f32x2*>(orow));
                        __builtin_nontemporal_store(o1, reinterpret_cast<f32x2*>(orow + 2));
                        __builtin_nontemporal_store(o2, reinterpret_cast<f32x2*>(orow + 4));
                        __builtin_nontemporal_store(o3, reinterpret_cast<f32x2*>(orow + 6));
                    }
                } else {
                    // c == 8184: outputs j=0..5 valid.
                    #pragma unroll
                    for (int j = 0; j < 6; ++j)
                        __builtin_nontemporal_store(acc[i][j], orow + j);
                }
            }
        }

        // Rotate rows: halo reuse. Full unroll -> pure register renaming.
        if (it + 1 < TILES) {
            #pragma unroll
            for (int q = 0; q < 10; ++q) {
                cur[0][q] = cur[4][q];
                cur[1][q] = cur[5][q];
            }
            #pragma unroll
            for (int t = 0; t < 4; ++t)
                #pragma unroll
                for (int q = 0; q < 10; ++q)
                    cur[2 + t][q] = nxt[t][q];
        }
    }
}

extern "C" void kernel_launch(void* const* d_in, const int* in_sizes, int n_in,
                              void* d_out, int out_size, void* d_ws, size_t ws_size,
                              hipStream_t stream) {
    const float* x    = (const float*)d_in[0];
    const float* w    = (const float*)d_in[1];
    const float* bias = (const float*)d_in[2];
    float* out        = (float*)d_out;

    dim3 block(64, 4, 1);
    dim3 grid((OW + 512 - 1) / 512,            // 16
              (OH + 32 - 1) / 32,              // 256
              1);
    conv3x3_kernel<<<grid, block, 0, stream>>>(x, w, bias, out);
}